// Round 5
// baseline (409.040 us; speedup 1.0000x reference)
//
#include <hip/hip_runtime.h>
#include <math.h>

// Problem constants (from reference)
#define VOCABN 8192
#define EMBN   80
#define UNITSN 2048
#define BATCHN 64
#define SEQN   64

// h rotation depth: consumer L2 staleness window = RBUF steps; one agent
// acquire fence (buffer_inv) per RBUF steps bounds staleness provably.
#define RBUF   4

typedef _Float16 f16;
typedef _Float16 f16x8 __attribute__((ext_vector_type(8)));
typedef float    f32x4 __attribute__((ext_vector_type(4)));

// LDS geometry: B-operand slice [32 uu][2176 k] f16, XOR-swizzled rows.
#define BROW 4352  // bytes per uu row; padded so swizzle stays in-row

// ws layout (bytes):
//   [0, 1048576)           : hbuf, RBUF x [64][2048] f16 (rotating h state)
//   [1048576, 1049600)     : flags, 4 groups x 64 WG monotonic step counters
//   [1049600, 1049856)     : out_pre, 64 floats (pre-sigmoid accumulators)
#define HBUF_BYTES   (RBUF * BATCHN * UNITSN * 2)
#define FLAGS_OFF    HBUF_BYTES
#define OUTPRE_OFF   (FLAGS_OFF + 4 * 64 * 4)
#define WS_ZERO_B    (OUTPRE_OFF + BATCHN * 4)

__device__ __forceinline__ f32x4 mfma16(f16x8 a, f16x8 b, f32x4 c) {
    return __builtin_amdgcn_mfma_f32_16x16x32_f16(a, b, c, 0, 0, 0);
}

// MALL-coherent (bypass L1+L2) primitives — used for h STORES and flags only.
// Consumer h reads are plain cached loads (see rotation-fence scheme above).
__device__ __forceinline__ int bypass_load_b32(const void* p) {
    int r;
    asm volatile("global_load_dword %0, %1, off sc0 sc1\n\ts_waitcnt vmcnt(0)"
                 : "=v"(r) : "v"(p) : "memory");
    return r;
}
__device__ __forceinline__ void bypass_store_b32(void* p, unsigned int v) {
    asm volatile("global_store_dword %0, %1, off sc0 sc1"
                 :: "v"(p), "v"(v) : "memory");
}

// Load cols [c0,c0+32) of W [2048 x 2048] (+ Wxp [80 x 2048] at k=2048..2143,
// zero-padded to 2144) as f16 into swizzled LDS: byte = uu*BROW + ((2k)^((uu&15)<<4)).
__device__ __forceinline__ void load_wslice(const float* __restrict__ W,
                                            const float* __restrict__ Wxp,
                                            int c0, int tid, unsigned char* Blds)
{
    const int j0 = tid >> 3, l8 = tid & 7;
    for (int it = 0; it < 64; ++it) {
        const int j = j0 + it * 32;
        const float4 w = *(const float4*)(W + (size_t)j * UNITSN + c0 + l8 * 4);
        const float vals[4] = {w.x, w.y, w.z, w.w};
#pragma unroll
        for (int q = 0; q < 4; ++q) {
            const int uu = l8 * 4 + q;
            *(f16*)(Blds + uu * BROW + ((2 * j) ^ ((uu & 15) << 4))) = (f16)vals[q];
        }
    }
    for (int j2 = j0; j2 < 96; j2 += 32) {
        float vals[4] = {0.f, 0.f, 0.f, 0.f};
        if (j2 < EMBN) {
            const float4 w = *(const float4*)(Wxp + (size_t)j2 * UNITSN + c0 + l8 * 4);
            vals[0] = w.x; vals[1] = w.y; vals[2] = w.z; vals[3] = w.w;
        }
#pragma unroll
        for (int q = 0; q < 4; ++q) {
            const int uu = l8 * 4 + q;
            const int k = 2048 + j2;
            *(f16*)(Blds + uu * BROW + ((2 * k) ^ ((uu & 15) << 4))) = (f16)vals[q];
        }
    }
}

// ---------------------------------------------------------------------------
// Recurrent kernel: 256 WGs = 4 row-groups (16 batch rows) x 64 col-chunks.
// Sync v4: bypass stores + bypass flags (as v3), but consumer h reads are
// CACHED against RBUF rotating buffers with one agent-acquire fence per
// rotation wrap -> first-touch-per-XCD misses only (~2 MB/step at MALL),
// 7/8 of reads become L2 hits.
// ---------------------------------------------------------------------------
__global__ __launch_bounds__(256)
void rnn_recur(const int* __restrict__ inputs, const float* __restrict__ emb,
               const float* __restrict__ Wx, const float* __restrict__ Wh,
               const float* __restrict__ bias, f16* __restrict__ hbuf,
               int* __restrict__ flags)
{
    __shared__ unsigned char Blds[32 * BROW];   // 139264 B
    __shared__ f16  xlds[2][16][96];            // 6144 B, double-buffered x_t
    __shared__ float red[4][2][64][4];          // 8192 B, per-wave MFMA partials
    __shared__ int  idxlds[16][SEQN];           // 4096 B, token ids

    const int tid = threadIdx.x;
    const int wg  = blockIdx.x;
    const int g     = wg >> 6;          // row group 0..3
    const int wslot = wg & 63;          // this WG's flag slot within group
    const int c0  = wslot * 32;         // output column base
    const int g16 = g * 16;

    for (int i = tid; i < 16 * SEQN; i += 256)
        idxlds[i >> 6][i & 63] = inputs[(g16 + (i >> 6)) * SEQN + (i & 63)];

    load_wslice(Wh, Wx, c0, tid, Blds);
    __syncthreads();

    // stage x_0
    {
        const int r  = tid >> 4;
        const int kb = (tid & 15) * 6;
        const float* erow = emb + (size_t)idxlds[r][0] * EMBN;
#pragma unroll
        for (int q = 0; q < 6; ++q) {
            const int k = kb + q;
            xlds[0][r][k] = (f16)((k < EMBN) ? erow[k] : 0.f);
        }
    }
    __syncthreads();

    const int lane = tid & 63;
    const int wv   = tid >> 6;      // wave 0..3: K-split
    const int l16  = lane & 15;
    const int lq   = lane >> 4;
    const int rr  = tid >> 4;       // reduce-phase output row 0..15
    const int cpa = (tid & 15) * 2; // reduce-phase output col pair
    const float ba = bias[c0 + cpa];
    const float bb = bias[c0 + cpa + 1];
    const int tla = cpa >> 4;
    const int la  = ((rr >> 2) << 4) + (cpa & 15);
    const int rg  = rr & 3;

    int* gflags = flags + g * 64;

    for (int t = 0; t < SEQN; ++t) {
        const int p  = t & 1;            // xlds parity
        const int rb = t & (RBUF - 1);   // h read buffer
        const int wb = (t + 1) & (RBUF - 1);  // h write buffer

        // Rotation wrap: invalidate L1/L2 so no cached h line can be older
        // than one rotation (covers cross-replay + own-XCD-store staleness).
        if (rb == 0)
            __builtin_amdgcn_fence(__ATOMIC_ACQUIRE, "agent");

        // MFMA: acc[16x32] = h_prev @ Wh0 + x_t @ Wx0 (K split by wave).
        // h fragments via PLAIN CACHED loads (freshness by rotation fence).
        f32x4 acc0 = {0.f, 0.f, 0.f, 0.f};
        f32x4 acc1 = {0.f, 0.f, 0.f, 0.f};
        {
            const f16* hrow = hbuf + (size_t)rb * BATCHN * UNITSN
                            + (size_t)(g16 + l16) * UNITSN + wv * 512 + lq * 8;
            const int swz = l16 << 4;
            const unsigned char* brow0 = Blds + l16 * BROW;
            const unsigned char* brow1 = Blds + (16 + l16) * BROW;
            f16x8 av[16];
#pragma unroll
            for (int kk = 0; kk < 16; ++kk)
                av[kk] = *(const f16x8*)(hrow + kk * 32);
            f16x8 ax;
            if (wv < 3) ax = *(const f16x8*)(&xlds[p][l16][wv * 32 + lq * 8]);
#pragma unroll
            for (int kk = 0; kk < 16; ++kk) {
                const int k0 = wv * 512 + kk * 32 + lq * 8;
                const int bo = (2 * k0) ^ swz;
                acc0 = mfma16(av[kk], *(const f16x8*)(brow0 + bo), acc0);
                acc1 = mfma16(av[kk], *(const f16x8*)(brow1 + bo), acc1);
            }
            if (wv < 3) {
                const int k0 = 2048 + wv * 32 + lq * 8;
                const int bo = (2 * k0) ^ swz;
                acc0 = mfma16(ax, *(const f16x8*)(brow0 + bo), acc0);
                acc1 = mfma16(ax, *(const f16x8*)(brow1 + bo), acc1);
            }
        }
        *(f32x4*)(&red[wv][0][lane][0]) = acc0;
        *(f32x4*)(&red[wv][1][lane][0]) = acc1;
        __syncthreads();

        // reduce 4 waves, bias, tanh, packed bypass store (to MALL)
        {
            float va = ba, vb = bb;
#pragma unroll
            for (int w = 0; w < 4; ++w) {
                va += red[w][tla][la][rg];
                vb += red[w][tla][la + 1][rg];
            }
            const f16 ha = (f16)tanhf(va);
            const f16 hb = (f16)tanhf(vb);
            const unsigned int pk = (unsigned int)__builtin_bit_cast(unsigned short, ha)
                                  | ((unsigned int)__builtin_bit_cast(unsigned short, hb) << 16);
            unsigned int* dst = (unsigned int*)(hbuf + (size_t)wb * BATCHN * UNITSN
                                                + (size_t)(g16 + rr) * UNITSN + c0 + cpa);
            bypass_store_b32(dst, pk);
        }
        // per-thread drain: h store acked at MALL before anyone passes barrier
        asm volatile("s_waitcnt vmcnt(0)" ::: "memory");
        __syncthreads();

        if (t == SEQN - 1) break;   // final h0 now in hbuf[buf 0]

        // publish: own slot, monotonic value, bypass store (no wbl2)
        if (tid == 0)
            bypass_store_b32(&gflags[wslot], (unsigned int)(t + 1));

        // overlap: stage x_{t+1} (cached; occasionally cold after wrap fence)
        {
            const int r  = tid >> 4;
            const int kb = (tid & 15) * 6;
            const float* erow = emb + (size_t)idxlds[r][t + 1] * EMBN;
            const int buf = (t + 1) & 1;
#pragma unroll
            for (int q = 0; q < 6; ++q) {
                const int k = kb + q;
                xlds[buf][r][k] = (f16)((k < EMBN) ? erow[k] : 0.f);
            }
        }

        // wave-0 poll: one 64-lane bypass load per round; no acquire fence
        if (wv == 0) {
            int tries = 0;
            for (;;) {
                const int v = bypass_load_b32(&gflags[lane]);
                if (__all(v > t)) break;
                __builtin_amdgcn_s_sleep(1);
                if (++tries > 150000) break;   // safety valve
            }
        }
        __syncthreads();   // releases waves 1..3; xlds[t+1] also ready
    }
}

// ---------------------------------------------------------------------------
// Final layer-5 at t=63 via MFMA: 64 WGs, each 32 cols x all 64 batch rows.
// h5 = tanh(x63@Wx5 + h0@Wh5 + b5); out_pre[r] += h5 . Wout (atomicAdd).
// h read: plain cached loads (kernel-dispatch acquire invalidates caches;
// validated empirically in rounds 1-2).
// ---------------------------------------------------------------------------
__global__ __launch_bounds__(256)
void final_gemm(const int* __restrict__ inputs, const float* __restrict__ emb,
                const float* __restrict__ Wx, const float* __restrict__ Wh,
                const float* __restrict__ bias, const float* __restrict__ Wout,
                const f16* __restrict__ hbuf, float* __restrict__ out_pre)
{
    __shared__ unsigned char Blds[32 * BROW];   // 139264 B
    __shared__ f16  xlds[64][96];               // 12288 B
    __shared__ float red[4][64][4];             // 4096 B (one col-tile pass)
    __shared__ float rowacc[64][4];             // 1024 B

    const int tid = threadIdx.x;
    const int c0  = blockIdx.x * 32;
    const float* Wh5 = Wh + (size_t)5 * UNITSN * UNITSN;
    const float* Wx5 = Wx + (size_t)5 * EMBN * UNITSN;
    const float* b5  = bias + 5 * UNITSN;

    load_wslice(Wh5, Wx5, c0, tid, Blds);
    // stage x_63 for all 64 rows
    {
        const int r  = tid >> 2;
        const int kb = (tid & 3) * 24;
        const float* erow = emb + (size_t)inputs[r * SEQN + SEQN - 1] * EMBN;
#pragma unroll
        for (int q = 0; q < 24; ++q) {
            const int k = kb + q;
            xlds[r][k] = (f16)((k < EMBN) ? erow[k] : 0.f);
        }
    }
    rowacc[tid >> 2][tid & 3] = 0.f;
    __syncthreads();

    const int lane = tid & 63;
    const int wv   = tid >> 6;
    const int l16  = lane & 15;
    const int lq   = lane >> 4;

    for (int ct = 0; ct < 2; ++ct) {
        f32x4 acc[4];
#pragma unroll
        for (int rt = 0; rt < 4; ++rt) acc[rt] = (f32x4){0.f, 0.f, 0.f, 0.f};
        const unsigned char* brow = Blds + (ct * 16 + l16) * BROW;
        const int swz = l16 << 4;
#pragma unroll
        for (int rt = 0; rt < 4; ++rt) {
            const f16* hrow = hbuf + (size_t)(rt * 16 + l16) * UNITSN + wv * 512 + lq * 8;
            f16x8 av[16];
#pragma unroll
            for (int kk = 0; kk < 16; ++kk)
                av[kk] = *(const f16x8*)(hrow + kk * 32);
            f16x8 ax;
            if (wv < 3) ax = *(const f16x8*)(&xlds[rt * 16 + l16][wv * 32 + lq * 8]);
#pragma unroll
            for (int kk = 0; kk < 16; ++kk) {
                const int k0 = wv * 512 + kk * 32 + lq * 8;
                acc[rt] = mfma16(av[kk], *(const f16x8*)(brow + ((2 * k0) ^ swz)), acc[rt]);
            }
            if (wv < 3) {
                const int k0 = 2048 + wv * 32 + lq * 8;
                acc[rt] = mfma16(ax, *(const f16x8*)(brow + ((2 * k0) ^ swz)), acc[rt]);
            }
        }
        // serialized cross-wave reduce into red (one-shot kernel; cost trivial)
        if (wv == 0) {
#pragma unroll
            for (int rt = 0; rt < 4; ++rt) *(f32x4*)(&red[rt][lane][0]) = acc[rt];
        }
        __syncthreads();
#pragma unroll
        for (int w = 1; w < 4; ++w) {
            if (wv == w) {
#pragma unroll
                for (int rt = 0; rt < 4; ++rt) {
                    f32x4 cur = *(f32x4*)(&red[rt][lane][0]);
                    cur += acc[rt];
                    *(f32x4*)(&red[rt][lane][0]) = cur;
                }
            }
            __syncthreads();
        }
        // consume: thread -> row r = tid>>2, 4 cols
        {
            const int r = tid >> 2;
            float rsum = 0.f;
#pragma unroll
            for (int q = 0; q < 4; ++q) {
                const int cl = (tid & 3) * 4 + q;
                const int c  = ct * 16 + cl;
                const int lidx = (((r & 15) >> 2) << 4) + cl;
                float v = red[r >> 4][lidx][r & 3] + b5[c0 + c];
                v = tanhf(v);
                rsum += v * Wout[c0 + c];
            }
            rowacc[r][tid & 3] += rsum;
        }
        __syncthreads();
    }
    if (tid < 64) {
        const float s = rowacc[tid][0] + rowacc[tid][1] + rowacc[tid][2] + rowacc[tid][3];
        atomicAdd(&out_pre[tid], s);
    }
}

__global__ void final_out(const float* __restrict__ out_pre,
                          const float* __restrict__ bout, float* __restrict__ out)
{
    const int b = threadIdx.x;
    if (b < BATCHN) out[b] = 1.f / (1.f + expf(-(out_pre[b] + bout[0])));
}

// ---------------------------------------------------------------------------
extern "C" void kernel_launch(void* const* d_in, const int* in_sizes, int n_in,
                              void* d_out, int out_size, void* d_ws, size_t ws_size,
                              hipStream_t stream) {
    (void)in_sizes; (void)n_in; (void)out_size; (void)ws_size;
    const int*   inputs = (const int*)d_in[0];
    const float* emb    = (const float*)d_in[1];
    const float* Wx     = (const float*)d_in[2];
    const float* Wh     = (const float*)d_in[3];
    const float* bias   = (const float*)d_in[4];
    const float* Wout   = (const float*)d_in[5];
    const float* bout   = (const float*)d_in[6];
    float* out = (float*)d_out;

    f16*   hbuf    = (f16*)d_ws;
    int*   flags   = (int*)((char*)d_ws + FLAGS_OFF);
    float* out_pre = (float*)((char*)d_ws + OUTPRE_OFF);

    // reset h state, flag slots, output accumulators (replay-deterministic)
    (void)hipMemsetAsync(d_ws, 0, WS_ZERO_B, stream);

    hipStreamCaptureStatus cs = hipStreamCaptureStatusNone;
    (void)hipStreamIsCapturing(stream, &cs);
    if (cs == hipStreamCaptureStatusActive) {
        rnn_recur<<<dim3(256), dim3(256), 0, stream>>>(inputs, emb, Wx, Wh, bias, hbuf, flags);
    } else {
        void* args[] = {(void*)&inputs, (void*)&emb, (void*)&Wx, (void*)&Wh,
                        (void*)&bias, (void*)&hbuf, (void*)&flags};
        hipError_t e = hipLaunchCooperativeKernel((const void*)rnn_recur, dim3(256), dim3(256),
                                                  args, 0, stream);
        if (e != hipSuccess) {
            rnn_recur<<<dim3(256), dim3(256), 0, stream>>>(inputs, emb, Wx, Wh, bias, hbuf, flags);
        }
    }
    final_gemm<<<dim3(64), dim3(256), 0, stream>>>(inputs, emb, Wx, Wh, bias, Wout, hbuf, out_pre);
    final_out<<<dim3(1), dim3(64), 0, stream>>>(out_pre, bout, out);
}

// Round 6
// 396.877 us; speedup vs baseline: 1.0306x; 1.0306x over previous
//
#include <hip/hip_runtime.h>
#include <math.h>

// Problem constants (from reference)
#define VOCABN 8192
#define EMBN   80
#define UNITSN 2048
#define BATCHN 64
#define SEQN   64

typedef _Float16 f16;
typedef _Float16 f16x8 __attribute__((ext_vector_type(8)));
typedef float    f32x4 __attribute__((ext_vector_type(4)));

// LDS geometry: B-operand slice [32 uu][2176 k] f16, XOR-swizzled rows.
#define BROW 4352  // bytes per uu row; padded so swizzle stays in-row

// hbuf layout (TILED to MFMA fragment order, all bypass traffic):
//   hbuf[p(2)][g(4)][kk(64)][lane(64)][8 f16]   -- 1 KB per (g,kk) tile
//   byte(p,g,kk) = ((p*4+g)<<16) + (kk<<10); lane fragment at +lane*16.
//   A k-tile kk holds h rows g*16..g*16+15, cols kk*32..kk*32+31, laid out so
//   consumer lane (lq<<4|l16) reads its own MFMA A-fragment contiguously and
//   producer WG (wslot==kk) writes its 32 cols as one contiguous 1 KB burst.
#define HBUF_BYTES   (2 * 4 * 64 * 1024)
#define FLAGS_OFF    HBUF_BYTES
#define OUTPRE_OFF   (FLAGS_OFF + 4 * 64 * 4)
#define WS_ZERO_B    (OUTPRE_OFF + BATCHN * 4)

__device__ __forceinline__ f32x4 mfma16(f16x8 a, f16x8 b, f32x4 c) {
    return __builtin_amdgcn_mfma_f32_16x16x32_f16(a, b, c, 0, 0, 0);
}

// MALL-coherent (bypass L1+L2) primitives — the ONLY way hbuf/flags are
// touched in the recurrent loop, so no cache maintenance is ever needed.
__device__ __forceinline__ void bypass_load_b16(f16x8* dst, const void* p) {
    asm volatile("global_load_dwordx4 %0, %1, off sc0 sc1"
                 : "=v"(*dst) : "v"(p) : "memory");
}
__device__ __forceinline__ int bypass_load_b32(const void* p) {
    int r;
    asm volatile("global_load_dword %0, %1, off sc0 sc1\n\ts_waitcnt vmcnt(0)"
                 : "=v"(r) : "v"(p) : "memory");
    return r;
}
__device__ __forceinline__ void bypass_store_b32(void* p, unsigned int v) {
    asm volatile("global_store_dword %0, %1, off sc0 sc1"
                 :: "v"(p), "v"(v) : "memory");
}
__device__ __forceinline__ void wait_vm0(void) {
    asm volatile("s_waitcnt vmcnt(0)" ::: "memory");
    __builtin_amdgcn_sched_barrier(0);
}

// Load cols [c0,c0+32) of W [2048 x 2048] (+ Wxp [80 x 2048] at k=2048..2143,
// zero-padded to 2144) as f16 into swizzled LDS: byte = uu*BROW + ((2k)^((uu&15)<<4)).
__device__ __forceinline__ void load_wslice(const float* __restrict__ W,
                                            const float* __restrict__ Wxp,
                                            int c0, int tid, unsigned char* Blds)
{
    const int j0 = tid >> 3, l8 = tid & 7;
    for (int it = 0; it < 64; ++it) {
        const int j = j0 + it * 32;
        const float4 w = *(const float4*)(W + (size_t)j * UNITSN + c0 + l8 * 4);
        const float vals[4] = {w.x, w.y, w.z, w.w};
#pragma unroll
        for (int q = 0; q < 4; ++q) {
            const int uu = l8 * 4 + q;
            *(f16*)(Blds + uu * BROW + ((2 * j) ^ ((uu & 15) << 4))) = (f16)vals[q];
        }
    }
    for (int j2 = j0; j2 < 96; j2 += 32) {
        float vals[4] = {0.f, 0.f, 0.f, 0.f};
        if (j2 < EMBN) {
            const float4 w = *(const float4*)(Wxp + (size_t)j2 * UNITSN + c0 + l8 * 4);
            vals[0] = w.x; vals[1] = w.y; vals[2] = w.z; vals[3] = w.w;
        }
#pragma unroll
        for (int q = 0; q < 4; ++q) {
            const int uu = l8 * 4 + q;
            const int k = 2048 + j2;
            *(f16*)(Blds + uu * BROW + ((2 * k) ^ ((uu & 15) << 4))) = (f16)vals[q];
        }
    }
}

// ---------------------------------------------------------------------------
// Recurrent kernel: 256 WGs = 4 row-groups (16 batch rows) x 64 col-chunks.
// Sync v5: all-bypass (v3) + hbuf retiled to fragment order so every h load
// and h store is a contiguous fully-coalesced burst (full 128B lines at the
// MALL, 8 lines per load instruction instead of 16 half-lines).
// ---------------------------------------------------------------------------
__global__ __launch_bounds__(256)
void rnn_recur(const int* __restrict__ inputs, const float* __restrict__ emb,
               const float* __restrict__ Wx, const float* __restrict__ Wh,
               const float* __restrict__ bias, f16* __restrict__ hbuf,
               int* __restrict__ flags)
{
    __shared__ unsigned char Blds[32 * BROW];   // 139264 B
    __shared__ float red[4][2][64][4];          // 8192 B, per-wave MFMA partials
    __shared__ int  idxlds[16][SEQN];           // 4096 B, token ids

    const int tid = threadIdx.x;
    const int wg  = blockIdx.x;
    const int g     = wg >> 6;          // row group 0..3
    const int wslot = wg & 63;          // this WG's flag slot == its k-tile
    const int c0  = wslot * 32;         // output column base
    const int g16 = g * 16;

    for (int i = tid; i < 16 * SEQN; i += 256)
        idxlds[i >> 6][i & 63] = inputs[(g16 + (i >> 6)) * SEQN + (i & 63)];

    load_wslice(Wh, Wx, c0, tid, Blds);
    __syncthreads();

    const int lane = tid & 63;
    const int wv   = tid >> 6;      // wave 0..3: K-split
    const int l16  = lane & 15;
    const int lq   = lane >> 4;
    const int rr  = tid >> 4;       // reduce-phase output row 0..15
    const int cpa = (tid & 15) * 2; // reduce-phase output col pair
    const float ba = bias[c0 + cpa];
    const float bb = bias[c0 + cpa + 1];
    const int tla = cpa >> 4;
    const int la  = ((rr >> 2) << 4) + (cpa & 15);
    const int rg  = rr & 3;
    // producer fragment slot for (rr, cpa) in the tiled layout
    const int lane_t = ((cpa >> 3) << 4) | rr;

    char* hb = (char*)hbuf;
    int* gflags = flags + g * 64;

    const int k0x = wv * 32 + lq * 8;                    // x k-offset, this lane
    const bool xvalid = (wv < 3) && (k0x < EMBN);        // full 8 floats iff true

    for (int t = 0; t < SEQN; ++t) {
        // all-wave poll: each wave independently waits for all 64 producers
        if (t > 0) {
            int tries = 0;
            for (;;) {
                const int v = bypass_load_b32(&gflags[lane]);
                if (__all(v >= t)) break;
                __builtin_amdgcn_s_sleep(1);
                if (++tries > 150000) break;   // safety valve
            }
        }

        // MFMA: acc[16x32] = h_prev @ Wh0 + x_t @ Wx0 (K split by wave).
        // h fragments: 16 contiguous 1 KB wave-bursts from the tiled buffer.
        f32x4 acc0 = {0.f, 0.f, 0.f, 0.f};
        f32x4 acc1 = {0.f, 0.f, 0.f, 0.f};
        {
            const char* hsrc = hb + (((t & 1) * 4 + g) << 16) + (lane << 4);
            f16x8 av[16];
#pragma unroll
            for (int kk = 0; kk < 16; ++kk)
                bypass_load_b16(&av[kk], hsrc + ((wv * 16 + kk) << 10));
            f16x8 ax = {0, 0, 0, 0, 0, 0, 0, 0};
            if (xvalid) {   // x_t fragment straight from emb (cached, L2-hot)
                const float* e = emb + (size_t)idxlds[l16][t] * EMBN + k0x;
                const float4 u = *(const float4*)e;
                const float4 w2 = *(const float4*)(e + 4);
                ax[0] = (f16)u.x;  ax[1] = (f16)u.y;  ax[2] = (f16)u.z;  ax[3] = (f16)u.w;
                ax[4] = (f16)w2.x; ax[5] = (f16)w2.y; ax[6] = (f16)w2.z; ax[7] = (f16)w2.w;
            }
            const int swz = l16 << 4;
            const unsigned char* brow0 = Blds + l16 * BROW;
            const unsigned char* brow1 = Blds + (16 + l16) * BROW;
            wait_vm0();
#pragma unroll
            for (int kk = 0; kk < 16; ++kk) {
                const int k0 = wv * 512 + kk * 32 + lq * 8;
                const int bo = (2 * k0) ^ swz;
                acc0 = mfma16(av[kk], *(const f16x8*)(brow0 + bo), acc0);
                acc1 = mfma16(av[kk], *(const f16x8*)(brow1 + bo), acc1);
            }
            if (wv < 3) {
                const int k0 = 2048 + wv * 32 + lq * 8;
                const int bo = (2 * k0) ^ swz;
                acc0 = mfma16(ax, *(const f16x8*)(brow0 + bo), acc0);
                acc1 = mfma16(ax, *(const f16x8*)(brow1 + bo), acc1);
            }
        }
        *(f32x4*)(&red[wv][0][lane][0]) = acc0;
        *(f32x4*)(&red[wv][1][lane][0]) = acc1;
        __syncthreads();

        // reduce 4 waves, bias, tanh, packed bypass store into own k-tile
        {
            float va = ba, vb = bb;
#pragma unroll
            for (int w = 0; w < 4; ++w) {
                va += red[w][tla][la][rg];
                vb += red[w][tla][la + 1][rg];
            }
            const f16 ha = (f16)tanhf(va);
            const f16 hbv = (f16)tanhf(vb);
            const unsigned int pk = (unsigned int)__builtin_bit_cast(unsigned short, ha)
                                  | ((unsigned int)__builtin_bit_cast(unsigned short, hbv) << 16);
            char* dst = hb + ((((t + 1) & 1) * 4 + g) << 16) + (wslot << 10)
                      + (lane_t << 4) + ((cpa & 7) << 1);
            bypass_store_b32(dst, pk);
        }
        // per-thread drain: tile store acked at MALL before anyone passes barrier
        asm volatile("s_waitcnt vmcnt(0)" ::: "memory");
        __syncthreads();

        // publish: own slot, monotonic value (flags memset 0 each launch)
        if (t < SEQN - 1 && tid == 0)
            bypass_store_b32(&gflags[wslot], (unsigned int)(t + 1));
    }
}

// ---------------------------------------------------------------------------
// Final layer-5 at t=63 via MFMA: 64 WGs, each 32 cols x all 64 batch rows.
// h5 = tanh(x63@Wx5 + h0@Wh5 + b5); out_pre[r] += h5 . Wout (atomicAdd).
// h read: plain cached loads from the tiled buffer (p=0; nothing stale in L2
// since recur never cache-reads hbuf, and values are replay-identical).
// ---------------------------------------------------------------------------
__global__ __launch_bounds__(256)
void final_gemm(const int* __restrict__ inputs, const float* __restrict__ emb,
                const float* __restrict__ Wx, const float* __restrict__ Wh,
                const float* __restrict__ bias, const float* __restrict__ Wout,
                const f16* __restrict__ hbuf, float* __restrict__ out_pre)
{
    __shared__ unsigned char Blds[32 * BROW];   // 139264 B
    __shared__ f16  xlds[64][96];               // 12288 B
    __shared__ float red[4][64][4];             // 4096 B (one col-tile pass)
    __shared__ float rowacc[64][4];             // 1024 B

    const int tid = threadIdx.x;
    const int c0  = blockIdx.x * 32;
    const float* Wh5 = Wh + (size_t)5 * UNITSN * UNITSN;
    const float* Wx5 = Wx + (size_t)5 * EMBN * UNITSN;
    const float* b5  = bias + 5 * UNITSN;
    const char* hb = (const char*)hbuf;

    load_wslice(Wh5, Wx5, c0, tid, Blds);
    // stage x_63 for all 64 rows
    {
        const int r  = tid >> 2;
        const int kb = (tid & 3) * 24;
        const float* erow = emb + (size_t)inputs[r * SEQN + SEQN - 1] * EMBN;
#pragma unroll
        for (int q = 0; q < 24; ++q) {
            const int k = kb + q;
            xlds[r][k] = (f16)((k < EMBN) ? erow[k] : 0.f);
        }
    }
    rowacc[tid >> 2][tid & 3] = 0.f;
    __syncthreads();

    const int lane = tid & 63;
    const int wv   = tid >> 6;
    const int l16  = lane & 15;
    const int lq   = lane >> 4;

    for (int ct = 0; ct < 2; ++ct) {
        f32x4 acc[4];
#pragma unroll
        for (int rt = 0; rt < 4; ++rt) acc[rt] = (f32x4){0.f, 0.f, 0.f, 0.f};
        const unsigned char* brow = Blds + (ct * 16 + l16) * BROW;
        const int swz = l16 << 4;
#pragma unroll
        for (int rt = 0; rt < 4; ++rt) {   // rt = row group in tiled hbuf (p=0)
            const char* hsrc = hb + (rt << 16) + (lane << 4);
            f16x8 av[16];
#pragma unroll
            for (int kk = 0; kk < 16; ++kk)
                av[kk] = *(const f16x8*)(hsrc + ((wv * 16 + kk) << 10));
            f16x8 ax;
            if (wv < 3) ax = *(const f16x8*)(&xlds[rt * 16 + l16][wv * 32 + lq * 8]);
#pragma unroll
            for (int kk = 0; kk < 16; ++kk) {
                const int k0 = wv * 512 + kk * 32 + lq * 8;
                acc[rt] = mfma16(av[kk], *(const f16x8*)(brow + ((2 * k0) ^ swz)), acc[rt]);
            }
            if (wv < 3) {
                const int k0 = 2048 + wv * 32 + lq * 8;
                acc[rt] = mfma16(ax, *(const f16x8*)(brow + ((2 * k0) ^ swz)), acc[rt]);
            }
        }
        // serialized cross-wave reduce into red (one-shot kernel; cost trivial)
        if (wv == 0) {
#pragma unroll
            for (int rt = 0; rt < 4; ++rt) *(f32x4*)(&red[rt][lane][0]) = acc[rt];
        }
        __syncthreads();
#pragma unroll
        for (int w = 1; w < 4; ++w) {
            if (wv == w) {
#pragma unroll
                for (int rt = 0; rt < 4; ++rt) {
                    f32x4 cur = *(f32x4*)(&red[rt][lane][0]);
                    cur += acc[rt];
                    *(f32x4*)(&red[rt][lane][0]) = cur;
                }
            }
            __syncthreads();
        }
        // consume: thread -> row r = tid>>2, 4 cols
        {
            const int r = tid >> 2;
            float rsum = 0.f;
#pragma unroll
            for (int q = 0; q < 4; ++q) {
                const int cl = (tid & 3) * 4 + q;
                const int c  = ct * 16 + cl;
                const int lidx = (((r & 15) >> 2) << 4) + cl;
                float v = red[r >> 4][lidx][r & 3] + b5[c0 + c];
                v = tanhf(v);
                rsum += v * Wout[c0 + c];
            }
            rowacc[r][tid & 3] += rsum;
        }
        __syncthreads();
    }
    if (tid < 64) {
        const float s = rowacc[tid][0] + rowacc[tid][1] + rowacc[tid][2] + rowacc[tid][3];
        atomicAdd(&out_pre[tid], s);
    }
}

__global__ void final_out(const float* __restrict__ out_pre,
                          const float* __restrict__ bout, float* __restrict__ out)
{
    const int b = threadIdx.x;
    if (b < BATCHN) out[b] = 1.f / (1.f + expf(-(out_pre[b] + bout[0])));
}

// ---------------------------------------------------------------------------
extern "C" void kernel_launch(void* const* d_in, const int* in_sizes, int n_in,
                              void* d_out, int out_size, void* d_ws, size_t ws_size,
                              hipStream_t stream) {
    (void)in_sizes; (void)n_in; (void)out_size; (void)ws_size;
    const int*   inputs = (const int*)d_in[0];
    const float* emb    = (const float*)d_in[1];
    const float* Wx     = (const float*)d_in[2];
    const float* Wh     = (const float*)d_in[3];
    const float* bias   = (const float*)d_in[4];
    const float* Wout   = (const float*)d_in[5];
    const float* bout   = (const float*)d_in[6];
    float* out = (float*)d_out;

    f16*   hbuf    = (f16*)d_ws;
    int*   flags   = (int*)((char*)d_ws + FLAGS_OFF);
    float* out_pre = (float*)((char*)d_ws + OUTPRE_OFF);

    // reset h state, flag slots, output accumulators (replay-deterministic)
    (void)hipMemsetAsync(d_ws, 0, WS_ZERO_B, stream);

    hipStreamCaptureStatus cs = hipStreamCaptureStatusNone;
    (void)hipStreamIsCapturing(stream, &cs);
    if (cs == hipStreamCaptureStatusActive) {
        rnn_recur<<<dim3(256), dim3(256), 0, stream>>>(inputs, emb, Wx, Wh, bias, hbuf, flags);
    } else {
        void* args[] = {(void*)&inputs, (void*)&emb, (void*)&Wx, (void*)&Wh,
                        (void*)&bias, (void*)&hbuf, (void*)&flags};
        hipError_t e = hipLaunchCooperativeKernel((const void*)rnn_recur, dim3(256), dim3(256),
                                                  args, 0, stream);
        if (e != hipSuccess) {
            rnn_recur<<<dim3(256), dim3(256), 0, stream>>>(inputs, emb, Wx, Wh, bias, hbuf, flags);
        }
    }
    final_gemm<<<dim3(64), dim3(256), 0, stream>>>(inputs, emb, Wx, Wh, bias, Wout, hbuf, out_pre);
    final_out<<<dim3(1), dim3(64), 0, stream>>>(out_pre, bout, out);
}

// Round 7
// 344.478 us; speedup vs baseline: 1.1874x; 1.1521x over previous
//
#include <hip/hip_runtime.h>
#include <math.h>

// Problem constants (from reference)
#define VOCABN 8192
#define EMBN   80
#define UNITSN 2048
#define BATCHN 64
#define SEQN   64

typedef _Float16 f16;
typedef _Float16 f16x8 __attribute__((ext_vector_type(8)));
typedef float    f32x4 __attribute__((ext_vector_type(4)));
typedef unsigned int u32x2 __attribute__((ext_vector_type(2)));

// LDS geometry for final_gemm's B slice (unchanged, proven)
#define BROW 4352

// hbuf layout (tiled to MFMA fragment order):
//   hbuf[p(2)][g(4)][kt(64)][lane(64)][8 f16]  -- 1 KB per (g,kt) tile
//   byte(p,g,kt) = ((p*4+g)<<16) + (kt<<10); lane fragment at +lane*16.
#define HBUF_BYTES   (2 * 4 * 64 * 1024)
#define FLAGS_OFF    HBUF_BYTES
#define OUTPRE_OFF   (FLAGS_OFF + 4 * 64 * 4)
#define WS_ZERO_B    (OUTPRE_OFF + BATCHN * 4)

// recur geometry: 128 WGs = 4 row-groups (16 rows) x 32 col-chunks (64 cols).
// K split over 4 waves: 2176 padded k = 4 x 544 = 4 x 17 tiles of 32.
#define KPW 544

__device__ __forceinline__ f32x4 mfma16(f16x8 a, f16x8 b, f32x4 c) {
    return __builtin_amdgcn_mfma_f32_16x16x32_f16(a, b, c, 0, 0, 0);
}

// MALL-coherent (bypass L1+L2) primitives — the ONLY way hbuf/flags are
// touched in the recurrent loop, so no cache maintenance is ever needed.
__device__ __forceinline__ void bypass_load_b16(f16x8* dst, const void* p) {
    asm volatile("global_load_dwordx4 %0, %1, off sc0 sc1"
                 : "=v"(*dst) : "v"(p) : "memory");
}
__device__ __forceinline__ int bypass_load_b32(const void* p) {
    int r;
    asm volatile("global_load_dword %0, %1, off sc0 sc1\n\ts_waitcnt vmcnt(0)"
                 : "=v"(r) : "v"(p) : "memory");
    return r;
}
__device__ __forceinline__ void bypass_store_b32(void* p, unsigned int v) {
    asm volatile("global_store_dword %0, %1, off sc0 sc1"
                 :: "v"(p), "v"(v) : "memory");
}
__device__ __forceinline__ void bypass_store_b64(void* p, u32x2 v) {
    asm volatile("global_store_dwordx2 %0, %1, off sc0 sc1"
                 :: "v"(p), "v"(v) : "memory");
}
__device__ __forceinline__ void wait_vm0(void) {
    asm volatile("s_waitcnt vmcnt(0)" ::: "memory");
    __builtin_amdgcn_sched_barrier(0);
}
__device__ __forceinline__ unsigned int us(f16 h) {
    return (unsigned int)__builtin_bit_cast(unsigned short, h);
}

// ---------------------------------------------------------------------------
// Recurrent kernel v6: register-resident weights (64 cols/WG, 128 WGs).
//   - B-operand: 17 ktiles x 4 coltiles x f16x8 = 272 VGPRs/wave, loaded once
//     via 3 LDS-staged chunks (coalesced f32 -> f16 -> register gather).
//   - per-step: 13..17 bypass tile-loads of h (1 KB contiguous bursts),
//     64-68 MFMAs, LDS cross-wave K-reduce, 4 tanh + one 8B bypass store,
//     flag publish + wave-0 poll (fan-in 32, one line per group).
//   - h read volume: 128 WG x 64 KB = 8 MB/step (was 16).
// ---------------------------------------------------------------------------
__global__ __launch_bounds__(256, 1)
void rnn_recur(const int* __restrict__ inputs, const float* __restrict__ emb,
               const float* __restrict__ Wx, const float* __restrict__ Wh,
               const float* __restrict__ bias, f16* __restrict__ hbuf,
               int* __restrict__ flags)
{
    // union region: prologue weight-staging Wtmp [768][65] f16 (99840 B),
    // then per-step reduce buffer red [4][4][64][4] f32 (16384 B).
    __shared__ __align__(16) char smem[99840];
    __shared__ f16  xlds[2][16][96];            // 6144 B, double-buffered x_t
    __shared__ int  idxlds[16][SEQN];           // 4096 B, token ids

    const int tid = threadIdx.x;
    const int wg  = blockIdx.x;
    const int g     = wg >> 5;          // row group 0..3 (rows 16g..16g+15)
    const int wslot = wg & 31;          // col-chunk 0..31
    const int c0  = wslot * 64;         // output column base
    const int g16 = g * 16;

    for (int i = tid; i < 16 * SEQN; i += 256)
        idxlds[i >> 6][i & 63] = inputs[(g16 + (i >> 6)) * SEQN + (i & 63)];

    const int lane = tid & 63;
    const int wv   = tid >> 6;      // wave 0..3: K-split
    const int l16  = lane & 15;
    const int lq   = lane >> 4;

    // ---- prologue: load Wh/Wx cols [c0,c0+64) into registers via LDS ----
    f16x8 b[17][4];
    {
        f16* Wtmp = (f16*)smem;     // [768][65]
        for (int ch = 0; ch < 3; ++ch) {
            const int base  = ch * 768;
            const int nrows = (base + 768 <= 2176) ? 768 : (2176 - base);
            for (int rp = 0; rp < nrows; rp += 16) {
                const int r_ = rp + (tid >> 4);
                if (r_ < nrows) {
                    const int k = base + r_;
                    float4 w = {0.f, 0.f, 0.f, 0.f};
                    if (k < UNITSN)
                        w = *(const float4*)(Wh + (size_t)k * UNITSN + c0 + (tid & 15) * 4);
                    else if (k - UNITSN < EMBN)
                        w = *(const float4*)(Wx + (size_t)(k - UNITSN) * UNITSN + c0 + (tid & 15) * 4);
                    f16* d = &Wtmp[r_ * 65 + (tid & 15) * 4];
                    d[0] = (f16)w.x; d[1] = (f16)w.y; d[2] = (f16)w.z; d[3] = (f16)w.w;
                }
            }
            __syncthreads();
#pragma unroll
            for (int i = 0; i < 17; ++i) {
                const int k = wv * KPW + i * 32;          // wave-uniform
                if (k >= base && k < base + 768) {
                    const int kl = k - base + lq * 8;
#pragma unroll
                    for (int ct = 0; ct < 4; ++ct) {
#pragma unroll
                        for (int e = 0; e < 8; ++e)
                            b[i][ct][e] = Wtmp[(kl + e) * 65 + ct * 16 + l16];
                    }
                }
            }
            __syncthreads();
        }
    }

    // stage x_0
    {
        const int r  = tid >> 4;
        const int kb = (tid & 15) * 6;
        const float* erow = emb + (size_t)idxlds[r][0] * EMBN;
#pragma unroll
        for (int q = 0; q < 6; ++q) {
            const int k = kb + q;
            xlds[0][r][k] = (f16)((k < EMBN) ? erow[k] : 0.f);
        }
    }
    __syncthreads();

    // reduce-phase mapping: thread -> (row rr, cols cb..cb+3)
    const int rr = tid >> 4;
    const int cb = (tid & 15) * 4;
    float bias4[4];
#pragma unroll
    for (int q = 0; q < 4; ++q) bias4[q] = bias[c0 + cb + q];
    // producer store address (tiled layout)
    const int gc     = c0 + cb;
    const int kt_p   = gc >> 5;
    const int cc     = gc & 31;
    const int lane_t = ((cc >> 3) << 4) | rr;
    const int pbyte  = lane_t * 16 + (cc & 7) * 2;

    char* hb = (char*)hbuf;
    int* gflags = flags + g * 32;
    float* red = (float*)smem;   // [4 wv][4 ct][64 lane][4]

    for (int t = 0; t < SEQN; ++t) {
        const int p = t & 1;

        // MFMA: acc[16x64] = h_prev @ Wh + x_t @ Wx, K split by wave.
        f32x4 acc[4];
#pragma unroll
        for (int ct = 0; ct < 4; ++ct) acc[ct] = (f32x4){0.f, 0.f, 0.f, 0.f};
        {
            const char* hsrc = hb + ((p * 4 + g) << 16) + (lane << 4);
            f16x8 av[17];
#pragma unroll
            for (int i = 0; i < 17; ++i) {
                if (wv * KPW + i * 32 < UNITSN)   // wave-uniform
                    bypass_load_b16(&av[i], hsrc + ((wv * 17 + i) << 10));
            }
            f16x8 axf0 = {}, axf1 = {}, axf2 = {};
            if (wv == 3) {   // x-part k = 2048..2143 lives in wave 3's range
                axf0 = *(const f16x8*)(&xlds[p][l16][0 * 32 + lq * 8]);
                axf1 = *(const f16x8*)(&xlds[p][l16][1 * 32 + lq * 8]);
                axf2 = *(const f16x8*)(&xlds[p][l16][2 * 32 + lq * 8]);
            }
            wait_vm0();
#pragma unroll
            for (int i = 0; i < 17; ++i) {
                if (wv * KPW + i * 32 < UNITSN) {
#pragma unroll
                    for (int ct = 0; ct < 4; ++ct)
                        acc[ct] = mfma16(av[i], b[i][ct], acc[ct]);
                }
            }
            if (wv == 3) {
#pragma unroll
                for (int ct = 0; ct < 4; ++ct) acc[ct] = mfma16(axf0, b[13][ct], acc[ct]);
#pragma unroll
                for (int ct = 0; ct < 4; ++ct) acc[ct] = mfma16(axf1, b[14][ct], acc[ct]);
#pragma unroll
                for (int ct = 0; ct < 4; ++ct) acc[ct] = mfma16(axf2, b[15][ct], acc[ct]);
            }
        }
#pragma unroll
        for (int ct = 0; ct < 4; ++ct)
            *(f32x4*)(&red[(((wv * 4) + ct) * 64 + lane) * 4]) = acc[ct];
        __syncthreads();

        // reduce 4 waves, bias, tanh, pack 4 f16, one 8B bypass store
        {
            float vv[4];
#pragma unroll
            for (int q = 0; q < 4; ++q) {
                const int c  = cb + q;
                const int tl = c >> 4;
                const int la = ((rr >> 2) << 4) | (c & 15);
                const int rg = rr & 3;
                float s = bias4[q];
#pragma unroll
                for (int w = 0; w < 4; ++w)
                    s += red[(((w * 4) + tl) * 64 + la) * 4 + rg];
                vv[q] = tanhf(s);
            }
            u32x2 pk;
            pk[0] = us((f16)vv[0]) | (us((f16)vv[1]) << 16);
            pk[1] = us((f16)vv[2]) | (us((f16)vv[3]) << 16);
            char* dst = hb + ((((t + 1) & 1) * 4 + g) << 16) + (kt_p << 10) + pbyte;
            bypass_store_b64(dst, pk);
        }
        // per-thread drain: h store acked at MALL before anyone passes barrier
        asm volatile("s_waitcnt vmcnt(0)" ::: "memory");
        __syncthreads();

        if (t == SEQN - 1) break;   // final h0 now in hbuf parity 0

        // publish: own slot, monotonic value (flags memset 0 each launch)
        if (tid == 0)
            bypass_store_b32(&gflags[wslot], (unsigned int)(t + 1));

        // overlap: stage x_{t+1} while the flags converge
        {
            const int r  = tid >> 4;
            const int kb = (tid & 15) * 6;
            const float* erow = emb + (size_t)idxlds[r][t + 1] * EMBN;
            const int buf = (t + 1) & 1;
#pragma unroll
            for (int q = 0; q < 6; ++q) {
                const int k = kb + q;
                xlds[buf][r][k] = (f16)((k < EMBN) ? erow[k] : 0.f);
            }
        }

        // wave-0 poll: 32 flags (one line), lanes 32-63 duplicate reads
        if (wv == 0) {
            int tries = 0;
            for (;;) {
                const int v = bypass_load_b32(&gflags[lane & 31]);
                if (__all(v > t)) break;
                __builtin_amdgcn_s_sleep(1);
                if (++tries > 150000) break;   // safety valve
            }
        }
        __syncthreads();   // releases waves 1..3; xlds[t+1] also ready
    }
}

// ---------------------------------------------------------------------------
// load_wslice for final_gemm (unchanged, proven): cols [c0,c0+32) of W + Wxp
// into swizzled LDS: byte = uu*BROW + ((2k)^((uu&15)<<4)).
// ---------------------------------------------------------------------------
__device__ __forceinline__ void load_wslice(const float* __restrict__ W,
                                            const float* __restrict__ Wxp,
                                            int c0, int tid, unsigned char* Blds)
{
    const int j0 = tid >> 3, l8 = tid & 7;
    for (int it = 0; it < 64; ++it) {
        const int j = j0 + it * 32;
        const float4 w = *(const float4*)(W + (size_t)j * UNITSN + c0 + l8 * 4);
        const float vals[4] = {w.x, w.y, w.z, w.w};
#pragma unroll
        for (int q = 0; q < 4; ++q) {
            const int uu = l8 * 4 + q;
            *(f16*)(Blds + uu * BROW + ((2 * j) ^ ((uu & 15) << 4))) = (f16)vals[q];
        }
    }
    for (int j2 = j0; j2 < 96; j2 += 32) {
        float vals[4] = {0.f, 0.f, 0.f, 0.f};
        if (j2 < EMBN) {
            const float4 w = *(const float4*)(Wxp + (size_t)j2 * UNITSN + c0 + l8 * 4);
            vals[0] = w.x; vals[1] = w.y; vals[2] = w.z; vals[3] = w.w;
        }
#pragma unroll
        for (int q = 0; q < 4; ++q) {
            const int uu = l8 * 4 + q;
            const int k = 2048 + j2;
            *(f16*)(Blds + uu * BROW + ((2 * k) ^ ((uu & 15) << 4))) = (f16)vals[q];
        }
    }
}

// ---------------------------------------------------------------------------
// Final layer-5 at t=63 via MFMA (unchanged from round 5/6; correct + fast).
// ---------------------------------------------------------------------------
__global__ __launch_bounds__(256)
void final_gemm(const int* __restrict__ inputs, const float* __restrict__ emb,
                const float* __restrict__ Wx, const float* __restrict__ Wh,
                const float* __restrict__ bias, const float* __restrict__ Wout,
                const f16* __restrict__ hbuf, float* __restrict__ out_pre)
{
    __shared__ unsigned char Blds[32 * BROW];   // 139264 B
    __shared__ f16  xlds[64][96];               // 12288 B
    __shared__ float red[4][64][4];             // 4096 B
    __shared__ float rowacc[64][4];             // 1024 B

    const int tid = threadIdx.x;
    const int c0  = blockIdx.x * 32;
    const float* Wh5 = Wh + (size_t)5 * UNITSN * UNITSN;
    const float* Wx5 = Wx + (size_t)5 * EMBN * UNITSN;
    const float* b5  = bias + 5 * UNITSN;
    const char* hb = (const char*)hbuf;

    load_wslice(Wh5, Wx5, c0, tid, Blds);
    {
        const int r  = tid >> 2;
        const int kb = (tid & 3) * 24;
        const float* erow = emb + (size_t)inputs[r * SEQN + SEQN - 1] * EMBN;
#pragma unroll
        for (int q = 0; q < 24; ++q) {
            const int k = kb + q;
            xlds[r][k] = (f16)((k < EMBN) ? erow[k] : 0.f);
        }
    }
    rowacc[tid >> 2][tid & 3] = 0.f;
    __syncthreads();

    const int lane = tid & 63;
    const int wv   = tid >> 6;
    const int l16  = lane & 15;
    const int lq   = lane >> 4;

    for (int ct = 0; ct < 2; ++ct) {
        f32x4 acc[4];
#pragma unroll
        for (int rt = 0; rt < 4; ++rt) acc[rt] = (f32x4){0.f, 0.f, 0.f, 0.f};
        const unsigned char* brow = Blds + (ct * 16 + l16) * BROW;
        const int swz = l16 << 4;
#pragma unroll
        for (int rt = 0; rt < 4; ++rt) {   // rt = row group in tiled hbuf (p=0)
            const char* hsrc = hb + (rt << 16) + (lane << 4);
            f16x8 av[16];
#pragma unroll
            for (int kk = 0; kk < 16; ++kk)
                av[kk] = *(const f16x8*)(hsrc + ((wv * 16 + kk) << 10));
            f16x8 ax;
            if (wv < 3) ax = *(const f16x8*)(&xlds[rt * 16 + l16][wv * 32 + lq * 8]);
#pragma unroll
            for (int kk = 0; kk < 16; ++kk) {
                const int k0 = wv * 512 + kk * 32 + lq * 8;
                acc[rt] = mfma16(av[kk], *(const f16x8*)(brow + ((2 * k0) ^ swz)), acc[rt]);
            }
            if (wv < 3) {
                const int k0 = 2048 + wv * 32 + lq * 8;
                acc[rt] = mfma16(ax, *(const f16x8*)(brow + ((2 * k0) ^ swz)), acc[rt]);
            }
        }
        if (wv == 0) {
#pragma unroll
            for (int rt = 0; rt < 4; ++rt) *(f32x4*)(&red[rt][lane][0]) = acc[rt];
        }
        __syncthreads();
#pragma unroll
        for (int w = 1; w < 4; ++w) {
            if (wv == w) {
#pragma unroll
                for (int rt = 0; rt < 4; ++rt) {
                    f32x4 cur = *(f32x4*)(&red[rt][lane][0]);
                    cur += acc[rt];
                    *(f32x4*)(&red[rt][lane][0]) = cur;
                }
            }
            __syncthreads();
        }
        {
            const int r = tid >> 2;
            float rsum = 0.f;
#pragma unroll
            for (int q = 0; q < 4; ++q) {
                const int cl = (tid & 3) * 4 + q;
                const int c  = ct * 16 + cl;
                const int lidx = (((r & 15) >> 2) << 4) + cl;
                float v = red[r >> 4][lidx][r & 3] + b5[c0 + c];
                v = tanhf(v);
                rsum += v * Wout[c0 + c];
            }
            rowacc[r][tid & 3] += rsum;
        }
        __syncthreads();
    }
    if (tid < 64) {
        const float s = rowacc[tid][0] + rowacc[tid][1] + rowacc[tid][2] + rowacc[tid][3];
        atomicAdd(&out_pre[tid], s);
    }
}

__global__ void final_out(const float* __restrict__ out_pre,
                          const float* __restrict__ bout, float* __restrict__ out)
{
    const int b = threadIdx.x;
    if (b < BATCHN) out[b] = 1.f / (1.f + expf(-(out_pre[b] + bout[0])));
}

// ---------------------------------------------------------------------------
extern "C" void kernel_launch(void* const* d_in, const int* in_sizes, int n_in,
                              void* d_out, int out_size, void* d_ws, size_t ws_size,
                              hipStream_t stream) {
    (void)in_sizes; (void)n_in; (void)out_size; (void)ws_size;
    const int*   inputs = (const int*)d_in[0];
    const float* emb    = (const float*)d_in[1];
    const float* Wx     = (const float*)d_in[2];
    const float* Wh     = (const float*)d_in[3];
    const float* bias   = (const float*)d_in[4];
    const float* Wout   = (const float*)d_in[5];
    const float* bout   = (const float*)d_in[6];
    float* out = (float*)d_out;

    f16*   hbuf    = (f16*)d_ws;
    int*   flags   = (int*)((char*)d_ws + FLAGS_OFF);
    float* out_pre = (float*)((char*)d_ws + OUTPRE_OFF);

    // reset h state, flag slots, output accumulators (replay-deterministic)
    (void)hipMemsetAsync(d_ws, 0, WS_ZERO_B, stream);

    hipStreamCaptureStatus cs = hipStreamCaptureStatusNone;
    (void)hipStreamIsCapturing(stream, &cs);
    if (cs == hipStreamCaptureStatusActive) {
        rnn_recur<<<dim3(128), dim3(256), 0, stream>>>(inputs, emb, Wx, Wh, bias, hbuf, flags);
    } else {
        void* args[] = {(void*)&inputs, (void*)&emb, (void*)&Wx, (void*)&Wh,
                        (void*)&bias, (void*)&hbuf, (void*)&flags};
        hipError_t e = hipLaunchCooperativeKernel((const void*)rnn_recur, dim3(128), dim3(256),
                                                  args, 0, stream);
        if (e != hipSuccess) {
            rnn_recur<<<dim3(128), dim3(256), 0, stream>>>(inputs, emb, Wx, Wh, bias, hbuf, flags);
        }
    }
    final_gemm<<<dim3(64), dim3(256), 0, stream>>>(inputs, emb, Wx, Wh, bias, Wout, hbuf, out_pre);
    final_out<<<dim3(1), dim3(64), 0, stream>>>(out_pre, bout, out);
}